// Round 5
// baseline (337.338 us; speedup 1.0000x reference)
//
#include <hip/hip_runtime.h>
#include <math.h>

namespace {
constexpr int B = 512, S = 64, K = 8, D = 16, NR = 64, NSTEPS = 100, NUNITS = 128;
}

// clang ext-vector int4: __builtin_nontemporal_load requires a real vector
// type (HIP's int4 is a class and is rejected).
typedef int i4 __attribute__((ext_vector_type(4)));

static __device__ __forceinline__ i4 ntload4(const int* p) {
    return __builtin_nontemporal_load((const i4*)p);
}

// Intra-wave LDS fence: same-wave DS ops complete in order; this waits for
// all outstanding LDS ops and stops the compiler reordering LDS accesses
// across it. Replaces __syncthreads() for wave-private LDS.
#define WAVE_LDS_FENCE() __asm__ volatile("s_waitcnt lgkmcnt(0)" ::: "memory")

// ---------------------------------------------------------------------------
// k_front R10 (heterogeneous): blocks [0,1024) = adjacency pipeline at FULL
// occupancy (one (p,k)-unit per thread: hop-1 scalar gather -> e1s/r0s,
// hop-2 row gather -> packed (e2<<6)|r1 stream). Blocks [1024,1536) = per-b
// diffusion MLP (+ w_tab scores + inline alpha schedule), writing the
// diffusion output rows of `out` directly. The MLP blocks' VALU work
// co-schedules with the gather blocks' memory latency on the same CUs —
// overlap that same-stream kernel serialization previously forbade.
// ---------------------------------------------------------------------------
__global__ __launch_bounds__(256) void k_front(
    const float* __restrict__ usr_emb, const float* __restrict__ rel_emb,
    const int* __restrict__ u, const int* __restrict__ t_arr,
    const int* __restrict__ click_seq,
    const int* __restrict__ adj_ent, const int* __restrict__ adj_rel,
    const float* __restrict__ noise_e,
    const float* __restrict__ W1, const float* __restrict__ b1,
    const float* __restrict__ W2, const float* __restrict__ b2,
    const float* __restrict__ W3, const float* __restrict__ b3,
    const float* __restrict__ W4, const float* __restrict__ b4,
    const float* __restrict__ se1, const float* __restrict__ se2,
    const float* __restrict__ se3,
    float* __restrict__ w_tab, int* __restrict__ e1s, int* __restrict__ r0s,
    int* __restrict__ e2r1, float* __restrict__ out)
{
    __shared__ float ur[D], xn[D], bet[NSTEPS], x0[D];
    __shared__ float v1[NUNITS], v2[NUNITS];
    __shared__ float pp[2][NUNITS];

    const int blk = blockIdx.x;
    const int tid = threadIdx.x;

    if (blk < 1024) {
        // ---- adjacency pipeline: unit = p*K + k, one per thread ----
        const int unit = blk * 256 + tid;          // [0, 262144)
        const int p = unit >> 3, k = unit & 7;
        const int e0 = click_seq[p];               // 8 lanes broadcast
        const int e1k = __builtin_nontemporal_load(adj_ent + (long)e0 * K + k);
        const int r0k = __builtin_nontemporal_load(adj_rel + (long)e0 * K + k);
        e1s[unit] = e1k;
        r0s[unit] = r0k;
        i4 x0v = ntload4(adj_ent + (long)e1k * K);
        i4 x1v = ntload4(adj_ent + (long)e1k * K + 4);
        i4 y0v = ntload4(adj_rel + (long)e1k * K);
        i4 y1v = ntload4(adj_rel + (long)e1k * K + 4);
        i4* o = (i4*)(e2r1 + (long)unit * K);
        o[0] = (x0v << 6) | y0v;                   // (e2<<6)|r1, elementwise
        o[1] = (x1v << 6) | y1v;
        return;
    }

    // ---- diffusion MLP + w_tab for b = blk - 1024 ----
    const int b = blk - 1024;
    const int t = tid & 127, h = tid >> 7;
    const int ts = t_arr[b];

    // phase 0: stage user row, noise row, beta terms
    if (tid < D) ur[tid] = usr_emb[(long)u[b] * D + tid];
    else if (tid >= 32 && tid < 32 + D) xn[tid - 32] = noise_e[(long)b * D + (tid - 32)];
    if (tid >= 64 && tid < 64 + NSTEPS) {
        int i = tid - 64;
        float x = -6.0f + (float)i * (12.0f / 99.0f);
        float sig = 1.0f / (1.0f + expf(-x));
        bet[i] = 1.0f - (sig * (0.005f - 1e-5f) + 1e-5f);
    }
    __syncthreads();

    // phase 0b: alpha product + x0 (16 threads, broadcast LDS reads)
    if (tid < D) {
        float prod = 1.0f;
        for (int i = 0; i <= ts; ++i) prod *= bet[i];
        float sa_ = sqrtf(prod), so_ = sqrtf(1.0f - prod);
        x0[tid] = ur[tid] * sa_ + xn[tid] * so_;
    }
    __syncthreads();

    // phase 1: L1 (tids 0-127) + w_tab scores (tids 128-191)
    if (h == 0) {
        float a = b1[t] + se1[(long)ts * NUNITS + t];
#pragma unroll
        for (int i = 0; i < D; ++i) a += x0[i] * W1[i * NUNITS + t];
        v1[t] = fmaxf(a, 0.0f);
    } else if (tid < 192) {
        int r = tid - 128;
        const float* rr = rel_emb + r * D;
        float s = 0.f;
#pragma unroll
        for (int d = 0; d < D; ++d) s += ur[d] * rr[d];
        w_tab[b * NR + r] = s * (1.0f / 16.0f);
    }
    __syncthreads();

    // phase 2: L2 partials (all 256; each half sums 64 of 128)
    {
        float part = 0.0f;
        const float* wp = W2 + (long)(64 * h) * NUNITS + t;
#pragma unroll 8
        for (int i = 0; i < 64; ++i) part += v1[64 * h + i] * wp[(long)i * NUNITS];
        pp[h][t] = part;
    }
    __syncthreads();

    // phase 3: v2 combine
    if (tid < NUNITS)
        v2[tid] = fmaxf(b2[tid] + se2[(long)ts * NUNITS + tid] + pp[0][tid] + pp[1][tid], 0.0f);
    __syncthreads();

    // phase 4: L3 partials
    {
        float part = 0.0f;
        const float* wp = W3 + (long)(64 * h) * NUNITS + t;
#pragma unroll 8
        for (int i = 0; i < 64; ++i) part += v2[64 * h + i] * wp[(long)i * NUNITS];
        pp[h][t] = part;
    }
    __syncthreads();

    // phase 5: v3 combine (reuse v1 storage; v1 fully consumed in phase 2)
    if (tid < NUNITS)
        v1[tid] = fmaxf(b3[tid] + se3[(long)ts * NUNITS + tid] + pp[0][tid] + pp[1][tid], 0.0f);
    __syncthreads();

    // phase 6: L4 partials (tids 0-31: two halves x 16 outputs)
    if (tid < 32) {
        int o = tid & 15, hh = tid >> 4;
        float acc = 0.0f;
#pragma unroll
        for (int i = 0; i < 64; ++i) acc += v1[64 * hh + i] * W4[(64 * hh + i) * D + o];
        pp[hh][o] = acc;
    }
    __syncthreads();

    // phase 7: diffusion output (no activation on the last layer)
    if (tid < D) out[(long)b * 17 + 1 + tid] = b4[tid] + pp[0][tid] + pp[1][tid];
}

// ---------------------------------------------------------------------------
// KGCN: byte-identical to the R9 version that passed (4 wave-private pairs
// per 256-thread block, zero block barriers; hop-2 indices from the packed
// e2r1 stream so the ent_emb gather chain is ONE random round-trip deep).
// ---------------------------------------------------------------------------
__global__ __launch_bounds__(256) void k_kgcn(
    const float* __restrict__ ent_emb,
    const float* __restrict__ w_tab,      // [B, NR]
    const int* __restrict__ click_seq,    // [B*S]
    const int* __restrict__ e1s,          // [B*S*K] precomputed
    const int* __restrict__ r0s,          // [B*S*K] precomputed
    const int* __restrict__ e2r1,         // [B*S*K*K] packed (e2<<6)|r1
    const float* __restrict__ agg_W,      // [D, D]
    const float* __restrict__ agg_b,      // [D]
    float* __restrict__ item)             // [B*S, D]
{
    __shared__ float wb[4][NR];
    __shared__ float Ws[4][D][D + 1];
    __shared__ float bs[4][D];
    __shared__ float Ms[4][K][D + 1];
    __shared__ float h1s[4][K][D + 1];
    __shared__ float h0s[4][D];
    __shared__ float A0s[4][D];
    __shared__ float M1s[4][D];
    __shared__ float p0s[4][K];

    const int tid = threadIdx.x;
    const int w = tid >> 6;             // wave in block, 0..3
    const int lane = tid & 63;
    const int p = blockIdx.x * 4 + w;   // pair id = b*S + s (64%4==0 -> same b)
    const int b = p >> 6;
    const int k = lane >> 3, j = lane & 7;

    // ---- index loads: all coalesced streams now (e2r1 warm from k_front)
    const int e0 = click_seq[p];
    const int e1k = e1s[(long)p * K + k];
    const int r0k = r0s[(long)p * K + k];
    const int pk = __builtin_nontemporal_load(e2r1 + (long)p * (K * K) + lane);
    const int e2kj = ((unsigned)pk) >> 6;
    const int r1kj = pk & 63;

    // ---- per-wave LDS staging (wave-private slab; no cross-wave sharing)
    {
        const float4 wv = ((const float4*)agg_W)[lane];     // agg_W[4l..4l+3]
        int row = lane >> 2, col = (lane & 3) * 4;
        Ws[w][row][col] = wv.x; Ws[w][row][col + 1] = wv.y;
        Ws[w][row][col + 2] = wv.z; Ws[w][row][col + 3] = wv.w;
        wb[w][lane] = w_tab[b * NR + lane];
        if (lane < D) bs[w][lane] = agg_b[lane];
    }
    WAVE_LDS_FENCE();   // wb/Ws/bs visible to this wave

    // ---- hop-1 softmax over j (masks 1,2,4 stay inside the 8-lane j-group)
    float s1 = wb[w][r1kj];
    float m1 = s1;
    m1 = fmaxf(m1, __shfl_xor(m1, 1));
    m1 = fmaxf(m1, __shfl_xor(m1, 2));
    m1 = fmaxf(m1, __shfl_xor(m1, 4));
    float ex = expf(s1 - m1);
    float den = ex;
    den += __shfl_xor(den, 1);
    den += __shfl_xor(den, 2);
    den += __shfl_xor(den, 4);
    float p1 = ex / den;

    // ---- gather rows: q2 (own), q1 (group-shared), q0 (wave-shared)
    float q2r[D], q1r[D], q0r[D];
    {
        const float4* q2p = (const float4*)(ent_emb + (long)e2kj * D);
        float4 a0 = q2p[0], a1 = q2p[1], a2 = q2p[2], a3 = q2p[3];
        q2r[0]=a0.x; q2r[1]=a0.y; q2r[2]=a0.z; q2r[3]=a0.w;
        q2r[4]=a1.x; q2r[5]=a1.y; q2r[6]=a1.z; q2r[7]=a1.w;
        q2r[8]=a2.x; q2r[9]=a2.y; q2r[10]=a2.z; q2r[11]=a2.w;
        q2r[12]=a3.x; q2r[13]=a3.y; q2r[14]=a3.z; q2r[15]=a3.w;
    }
    {
        const float4* q1p = (const float4*)(ent_emb + (long)e1k * D);
        float4 a0 = q1p[0], a1 = q1p[1], a2 = q1p[2], a3 = q1p[3];
        q1r[0]=a0.x; q1r[1]=a0.y; q1r[2]=a0.z; q1r[3]=a0.w;
        q1r[4]=a1.x; q1r[5]=a1.y; q1r[6]=a1.z; q1r[7]=a1.w;
        q1r[8]=a2.x; q1r[9]=a2.y; q1r[10]=a2.z; q1r[11]=a2.w;
        q1r[12]=a3.x; q1r[13]=a3.y; q1r[14]=a3.z; q1r[15]=a3.w;
    }
    {
        const float4* q0p = (const float4*)(ent_emb + (long)e0 * D);
        float4 a0 = q0p[0], a1 = q0p[1], a2 = q0p[2], a3 = q0p[3];
        q0r[0]=a0.x; q0r[1]=a0.y; q0r[2]=a0.z; q0r[3]=a0.w;
        q0r[4]=a1.x; q0r[5]=a1.y; q0r[6]=a1.z; q0r[7]=a1.w;
        q0r[8]=a2.x; q0r[9]=a2.y; q0r[10]=a2.z; q0r[11]=a2.w;
        q0r[12]=a3.x; q0r[13]=a3.y; q0r[14]=a3.z; q0r[15]=a3.w;
    }

    // ---- hop-1 j-reduction (reduce-scatter, masks 1,2,4). Lane keeps the
    // half it will own; final 2 dims at dbase = 8(j&1)+4(j>>1&1)+2(j>>2&1).
    {
        float cur[16];
#pragma unroll
        for (int d = 0; d < 16; ++d) cur[d] = p1 * q2r[d];
        const bool b0 = (lane & 1), b1 = (lane & 2), b2 = (lane & 4);
        float n8[8];
#pragma unroll
        for (int d = 0; d < 8; ++d) {
            float snd = b0 ? cur[d] : cur[d + 8];
            float kp  = b0 ? cur[d + 8] : cur[d];
            n8[d] = kp + __shfl_xor(snd, 1);
        }
        float n4[4];
#pragma unroll
        for (int d = 0; d < 4; ++d) {
            float snd = b1 ? n8[d] : n8[d + 4];
            float kp  = b1 ? n8[d + 4] : n8[d];
            n4[d] = kp + __shfl_xor(snd, 2);
        }
        float a0 = (b2 ? n4[2] : n4[0]) + __shfl_xor(b2 ? n4[0] : n4[2], 4);
        float a1 = (b2 ? n4[3] : n4[1]) + __shfl_xor(b2 ? n4[1] : n4[3], 4);
        const int dbase = (b0 ? 8 : 0) + (b1 ? 4 : 0) + (b2 ? 2 : 0);
        Ms[w][k][dbase]     = q1r[dbase]     + a0;   // self + neigh_agg
        Ms[w][k][dbase + 1] = q1r[dbase + 1] + a1;
    }

    // ---- hop-0 softmax over k (masks 8,16,32 keep j fixed)
    float s0 = wb[w][r0k];
    float m0 = s0;
    m0 = fmaxf(m0, __shfl_xor(m0, 8));
    m0 = fmaxf(m0, __shfl_xor(m0, 16));
    m0 = fmaxf(m0, __shfl_xor(m0, 32));
    float e0x = expf(s0 - m0);
    float d0 = e0x;
    d0 += __shfl_xor(d0, 8);
    d0 += __shfl_xor(d0, 16);
    d0 += __shfl_xor(d0, 32);
    float p0 = e0x / d0;
    if (j == 0) p0s[w][k] = p0;

    // ---- ag0 = sum_k p0_k * q1[k]: reduce-scatter over k (masks 8,16,32);
    // identical values across j, so j==0 lanes deposit the 16 dims in A0s.
    {
        float cur[16];
#pragma unroll
        for (int d = 0; d < 16; ++d) cur[d] = p0 * q1r[d];
        const bool c0 = (lane & 8), c1 = (lane & 16), c2 = (lane & 32);
        float n8[8];
#pragma unroll
        for (int d = 0; d < 8; ++d) {
            float snd = c0 ? cur[d] : cur[d + 8];
            float kp  = c0 ? cur[d + 8] : cur[d];
            n8[d] = kp + __shfl_xor(snd, 8);
        }
        float n4[4];
#pragma unroll
        for (int d = 0; d < 4; ++d) {
            float snd = c1 ? n8[d] : n8[d + 4];
            float kp  = c1 ? n8[d + 4] : n8[d];
            n4[d] = kp + __shfl_xor(snd, 16);
        }
        float a0 = (c2 ? n4[2] : n4[0]) + __shfl_xor(c2 ? n4[0] : n4[2], 32);
        float a1 = (c2 ? n4[3] : n4[1]) + __shfl_xor(c2 ? n4[1] : n4[3], 32);
        const int dbase = (c0 ? 8 : 0) + (c1 ? 4 : 0) + (c2 ? 2 : 0);
        if (j == 0) { A0s[w][dbase] = a0; A0s[w][dbase + 1] = a1; }
    }
    WAVE_LDS_FENCE();   // Ms, A0s, p0s ready

    // ---- h1[k] = sigmoid(M[k] @ W + b): 128 outputs over 64 lanes (2 each)
#pragma unroll
    for (int o = lane; o < 128; o += 64) {
        int ko = o >> 4, dd = o & 15;
        float acc = bs[w][dd];
#pragma unroll
        for (int din = 0; din < D; ++din) acc += Ms[w][ko][din] * Ws[w][din][dd];
        h1s[w][ko][dd] = 1.0f / (1.0f + expf(-acc));
    }

    // ---- h0 = sigmoid((q0 + ag0) @ W + b)
    const int ddl = lane & 15;
    {
        float acc = bs[w][ddl];
#pragma unroll
        for (int din = 0; din < D; ++din)
            acc += (q0r[din] + A0s[w][din]) * Ws[w][din][ddl];
        if (lane < D) h0s[w][lane] = 1.0f / (1.0f + expf(-acc));
    }
    WAVE_LDS_FENCE();   // h1s, h0s ready

    // ---- iteration 1 input vector: M1 = h0 + sum_k p0_k * h1[k]
    if (lane < D) {
        float m = h0s[w][lane];
#pragma unroll
        for (int kk = 0; kk < K; ++kk) m += p0s[w][kk] * h1s[w][kk][lane];
        M1s[w][lane] = m;
    }
    WAVE_LDS_FENCE();   // M1s ready

    // ---- final: relu(tanh(M1 @ W + b))
    {
        float acc = bs[w][ddl];
#pragma unroll
        for (int din = 0; din < D; ++din) acc += M1s[w][din] * Ws[w][din][ddl];
        if (lane < D) item[(long)p * D + lane] = fmaxf(tanhf(acc), 0.0f);
    }
}

// ---------------------------------------------------------------------------
// k_back R10: fusion head only, ONE 64-lane wave per b (no __syncthreads —
// wave-private LDS + fences). Reads item (L2-warm from k_kgcn), writes the
// sigmoid output column. Diffusion outputs were already written by k_front.
// ---------------------------------------------------------------------------
__global__ __launch_bounds__(64) void k_back(
    const float* __restrict__ item,     // [B*S, D]
    const float* __restrict__ fc1_W, const float* __restrict__ fc1_b,
    const float* __restrict__ fc2_W, const float* __restrict__ fc2_b,
    const float* __restrict__ ent_emb, const int* __restrict__ v,
    float* __restrict__ out)            // [B, 17]
{
    __shared__ float sm[S][D + 1];
    __shared__ float fus[2 * D];
    __shared__ float hid[64];

    const int b = blockIdx.x, t = threadIdx.x;   // one wave

    // stage item rows (row t per lane)
    {
        const float4* ip = (const float4*)(item + ((long)b * S + t) * D);
        float4 r0 = ip[0], r1 = ip[1], r2 = ip[2], r3 = ip[3];
        sm[t][0]=r0.x;  sm[t][1]=r0.y;  sm[t][2]=r0.z;  sm[t][3]=r0.w;
        sm[t][4]=r1.x;  sm[t][5]=r1.y;  sm[t][6]=r1.z;  sm[t][7]=r1.w;
        sm[t][8]=r2.x;  sm[t][9]=r2.y;  sm[t][10]=r2.z; sm[t][11]=r2.w;
        sm[t][12]=r3.x; sm[t][13]=r3.y; sm[t][14]=r3.z; sm[t][15]=r3.w;
    }
    WAVE_LDS_FENCE();

    // fus = [relu(sum_s), relu(max_s)]
    if (t < D) {
        float sv = 0.0f, mv = -1e30f;
#pragma unroll
        for (int ss = 0; ss < S; ++ss) {
            float x = sm[ss][t];
            sv += x;
            mv = fmaxf(mv, x);
        }
        fus[t] = fmaxf(sv, 0.0f);
        fus[D + t] = fmaxf(mv, 0.0f);
    }
    WAVE_LDS_FENCE();

    // hid = relu(fus @ fc1_W + fc1_b)  (64 outputs, one per lane)
    {
        float acc = fc1_b[t];
#pragma unroll
        for (int i = 0; i < 2 * D; ++i) acc += fus[i] * fc1_W[i * 64 + t];
        hid[t] = fmaxf(acc, 0.0f);
    }
    WAVE_LDS_FENCE();

    // feat = relu(hid @ fc2_W + fc2_b); dot with ent_emb[v[b]]; sigmoid
    if (t < D) {
        float f = fc2_b[t];
#pragma unroll
        for (int i = 0; i < 64; ++i) f += hid[i] * fc2_W[i * D + t];
        f = fmaxf(f, 0.0f);
        float g = f * ent_emb[(long)v[b] * D + t];
        g += __shfl_xor(g, 1);
        g += __shfl_xor(g, 2);
        g += __shfl_xor(g, 4);
        g += __shfl_xor(g, 8);
        if (t == 0) out[(long)b * 17] = 1.0f / (1.0f + expf(-g));
    }
}

// ---------------------------------------------------------------------------
extern "C" void kernel_launch(void* const* d_in, const int* in_sizes, int n_in,
                              void* d_out, int out_size, void* d_ws, size_t ws_size,
                              hipStream_t stream) {
    const float* usr_emb = (const float*)d_in[0];
    const float* ent_emb = (const float*)d_in[1];
    const float* rel_emb = (const float*)d_in[2];
    const float* agg_W   = (const float*)d_in[3];
    const float* agg_b   = (const float*)d_in[4];
    const float* fc1_W   = (const float*)d_in[5];
    const float* fc1_b   = (const float*)d_in[6];
    const float* fc2_W   = (const float*)d_in[7];
    const float* fc2_b   = (const float*)d_in[8];
    const float* mlp_W1  = (const float*)d_in[9];
    const float* mlp_b1  = (const float*)d_in[10];
    const float* mlp_W2  = (const float*)d_in[11];
    const float* mlp_b2  = (const float*)d_in[12];
    const float* mlp_W3  = (const float*)d_in[13];
    const float* mlp_b3  = (const float*)d_in[14];
    const float* mlp_W4  = (const float*)d_in[15];
    const float* mlp_b4  = (const float*)d_in[16];
    const float* se1     = (const float*)d_in[17];
    const float* se2     = (const float*)d_in[18];
    const float* se3     = (const float*)d_in[19];
    const float* noise_e = (const float*)d_in[20];
    const int* u         = (const int*)d_in[21];
    const int* v         = (const int*)d_in[22];
    const int* click_seq = (const int*)d_in[23];
    const int* adj_ent   = (const int*)d_in[24];
    const int* adj_rel   = (const int*)d_in[25];
    const int* t         = (const int*)d_in[26];
    float* out = (float*)d_out;

    float* ws = (float*)d_ws;
    float* w_tab = ws;                         // B*NR floats
    float* item  = w_tab + B * NR;             // B*S*D floats (2 MB)
    int*   e1s   = (int*)(item + B * S * D);   // B*S*K ints (1 MB)
    int*   r0s   = e1s + B * S * K;            // B*S*K ints (1 MB)
    int*   e2r1  = r0s + B * S * K;            // B*S*K*K ints (8 MB, packed)

    k_front<<<1536, 256, 0, stream>>>(usr_emb, rel_emb, u, t, click_seq, adj_ent, adj_rel,
                                      noise_e, mlp_W1, mlp_b1, mlp_W2, mlp_b2,
                                      mlp_W3, mlp_b3, mlp_W4, mlp_b4, se1, se2, se3,
                                      w_tab, e1s, r0s, e2r1, out);
    k_kgcn<<<(B * S) / 4, 256, 0, stream>>>(ent_emb, w_tab, click_seq,
                                            e1s, r0s, e2r1, agg_W, agg_b, item);
    k_back<<<B, 64, 0, stream>>>(item, fc1_W, fc1_b, fc2_W, fc2_b, ent_emb, v, out);
}